// Round 2
// baseline (302.083 us; speedup 1.0000x reference)
//
#include <hip/hip_runtime.h>
#include <hip/hip_bf16.h>

// GAT layer: B=32, N=1024, IN_F=OUT_F=256, alpha=0.2
//  k1: WhT[b][o][n] = bf16(h @ W^T), MFMA; epilogue via LDS -> coalesced 128B
//      row-segment writes; fused si/sj (= Wh @ a1/a2), pre-scaled by log2(e)
//  k3: fused adj-read + masked-softmax attention + PV MFMA + ELU.
//      32-row i-tiles, grid 1024 -> 4 blocks/CU (~50% occupancy) for latency
//      hiding; adj/sj prefetch double-buffered in registers with static names;
//      whT read straight from L2-resident global; S-tile double-buffered in
//      LDS -> one barrier per j-chunk.

#define ALPHA 0.2f
#define LOG2E 1.44269504f

typedef __bf16 bf16x8 __attribute__((ext_vector_type(8)));
typedef __bf16 bf16x4 __attribute__((ext_vector_type(4)));
typedef float  f32x4  __attribute__((ext_vector_type(4)));
typedef unsigned long long u64;

// ---------------- k1: Wh = h @ W^T -> whT (bf16) + si/sj ----------------
// grid 512 x 256 thr; block = 64 n-rows x 256 o, K chunks of 64, reg-prefetched.
__global__ __launch_bounds__(256) void k1_gemm1(const float* __restrict__ h,
                                                const float* __restrict__ W,
                                                const float* __restrict__ a_g,
                                                __bf16* __restrict__ whT,
                                                float* __restrict__ si,
                                                float* __restrict__ sj) {
    __shared__ __bf16 hA[64 * 72];
    __shared__ __bf16 hB[256 * 72];   // W tiles; reused as [o][n] out-staging
    __shared__ float  red[512];
    const int t    = threadIdx.x;
    const int r0   = blockIdx.x * 64;
    const int b    = r0 >> 10;
    const int n0   = r0 & 1023;
    const int w    = t >> 6;
    const int l    = t & 63;
    const int ln   = l & 15;
    const int quad = l >> 4;

    f32x4 acc[4][4] = {};
    float4 ha_r[4], wb_r[16];

    // preload chunk 0
    #pragma unroll
    for (int it = 0; it < 4; ++it)
        ha_r[it] = *(const float4*)&h[(size_t)(r0 + it * 16 + (t >> 4)) * 256 + (t & 15) * 4];
    #pragma unroll
    for (int it = 0; it < 16; ++it)
        wb_r[it] = *(const float4*)&W[(size_t)(it * 16 + (t >> 4)) * 256 + (t & 15) * 4];

    for (int kc = 0; kc < 4; ++kc) {
        // write staged chunk to LDS (fp32 -> bf16)
        #pragma unroll
        for (int it = 0; it < 4; ++it) {
            const float4 v = ha_r[it];
            bf16x4 pv = {(__bf16)v.x, (__bf16)v.y, (__bf16)v.z, (__bf16)v.w};
            *(bf16x4*)&hA[(it * 16 + (t >> 4)) * 72 + (t & 15) * 4] = pv;
        }
        #pragma unroll
        for (int it = 0; it < 16; ++it) {
            const float4 v = wb_r[it];
            bf16x4 pv = {(__bf16)v.x, (__bf16)v.y, (__bf16)v.z, (__bf16)v.w};
            *(bf16x4*)&hB[(it * 16 + (t >> 4)) * 72 + (t & 15) * 4] = pv;
        }
        __syncthreads();
        // prefetch next chunk while MFMA runs
        if (kc < 3) {
            const int k0 = (kc + 1) * 64;
            #pragma unroll
            for (int it = 0; it < 4; ++it)
                ha_r[it] = *(const float4*)&h[(size_t)(r0 + it * 16 + (t >> 4)) * 256 + k0 + (t & 15) * 4];
            #pragma unroll
            for (int it = 0; it < 16; ++it)
                wb_r[it] = *(const float4*)&W[(size_t)(it * 16 + (t >> 4)) * 256 + k0 + (t & 15) * 4];
        }
        #pragma unroll
        for (int kk = 0; kk < 2; ++kk) {
            bf16x8 af[4], bfr[4];
            #pragma unroll
            for (int ri = 0; ri < 4; ++ri)
                af[ri] = *(const bf16x8*)&hA[(ri * 16 + ln) * 72 + kk * 32 + quad * 8];
            #pragma unroll
            for (int oi = 0; oi < 4; ++oi)
                bfr[oi] = *(const bf16x8*)&hB[(w * 64 + oi * 16 + ln) * 72 + kk * 32 + quad * 8];
            #pragma unroll
            for (int ri = 0; ri < 4; ++ri)
                #pragma unroll
                for (int oi = 0; oi < 4; ++oi)
                    acc[ri][oi] = __builtin_amdgcn_mfma_f32_16x16x32_bf16(
                        af[ri], bfr[oi], acc[ri][oi], 0, 0, 0);
        }
        __syncthreads();
    }

    // stage acc -> hB as [o][n_local] (stride 72, conflict-light)
    #pragma unroll
    for (int ri = 0; ri < 4; ++ri) {
        const int n = ri * 16 + quad * 4;
        #pragma unroll
        for (int oi = 0; oi < 4; ++oi) {
            const int o = w * 64 + oi * 16 + ln;
            bf16x4 pv = {(__bf16)acc[ri][oi][0], (__bf16)acc[ri][oi][1],
                         (__bf16)acc[ri][oi][2], (__bf16)acc[ri][oi][3]};
            *(bf16x4*)&hB[o * 72 + n] = pv;
        }
    }
    __syncthreads();

    // whT writes: wave w covers o in [w*64, w*64+64); 8 rows x 128B per instr
    #pragma unroll
    for (int it = 0; it < 8; ++it) {
        const int o   = w * 64 + it * 8 + (l >> 3);
        const int seg = l & 7;
        const bf16x8 v = *(const bf16x8*)&hB[o * 72 + seg * 8];
        *(bf16x8*)&whT[((size_t)b * 256 + o) * 1024 + n0 + seg * 8] = v;
    }

    // fused si/sj: wave w sums o-range [w*64, w*64+64) for n = lane
    {
        float s1 = 0.f, s2 = 0.f;
        #pragma unroll 8
        for (int oi = 0; oi < 64; ++oi) {
            const int o = w * 64 + oi;
            const float v = (float)hB[o * 72 + l];
            s1 += v * a_g[o];
            s2 += v * a_g[256 + o];
        }
        red[w * 64 + l]       = s1;
        red[256 + w * 64 + l] = s2;
    }
    __syncthreads();
    // pre-scale by log2(e): leaky-relu commutes with a positive scale, so
    // k3 can use native v_exp_f32 (exp2f) directly.
    if (t < 64) {
        si[b * 1024 + n0 + t] =
            (red[t] + red[64 + t] + red[128 + t] + red[192 + t]) * LOG2E;
    } else if (t < 128) {
        const int n = t - 64;
        sj[b * 1024 + n0 + n] =
            (red[256 + n] + red[320 + n] + red[384 + n] + red[448 + n]) * LOG2E;
    }
}

// ---------------- k3: fused attention (32-row tiles, 4 blocks/CU) ----------------
// grid 1024 (XCD-chunked), 256 thr (4 waves). One barrier per j-chunk.
// Per-jc body macro: static register names for the double-buffered adj/sj
// prefetch (rule #20: no runtime-indexed ext_vector arrays).
#define K3_BODY(JC, ACUR, SJCUR, ANXT, SJNXT, SBUF)                                    \
  {                                                                                    \
    const int j0 = (JC) * 64;                                                          \
    /* B-fragments for this chunk (L2-resident whT; latency hidden under S) */         \
    bf16x8 bfr[2][4];                                                                  \
    _Pragma("unroll")                                                                  \
    for (int kk = 0; kk < 2; ++kk)                                                     \
      _Pragma("unroll")                                                                \
      for (int oi = 0; oi < 4; ++oi)                                                   \
        bfr[kk][oi] = *(const bf16x8*)&whTb[                                           \
            (size_t)(w * 64 + oi * 16 + ln) * 1024 + j0 + kk * 32 + quad * 8];         \
    /* prefetch next adj/sj chunk early: whole S+barrier+MFMA window to land */        \
    if ((JC) < 15) {                                                                   \
      _Pragma("unroll")                                                                \
      for (int m = 0; m < 2; ++m)                                                      \
        ANXT[m] = *(const int4*)&adjb[(size_t)(m * 16 + g) * 1024 + j0 + 64 + j4 * 4]; \
      SJNXT = *(const float4*)&sj_g[b * 1024 + j0 + 64 + j4 * 4];                      \
    }                                                                                  \
    /* S tile: w = adj ? exp2(leakyrelu(si+sj)) : 0   (si/sj pre-scaled) */            \
    _Pragma("unroll")                                                                  \
    for (int m = 0; m < 2; ++m) {                                                      \
      const int il = m * 16 + g;                                                       \
      float e0 = si_r[m] + SJCUR.x; e0 = e0 > 0.f ? e0 : ALPHA * e0;                   \
      float e1 = si_r[m] + SJCUR.y; e1 = e1 > 0.f ? e1 : ALPHA * e1;                   \
      float e2 = si_r[m] + SJCUR.z; e2 = e2 > 0.f ? e2 : ALPHA * e2;                   \
      float e3 = si_r[m] + SJCUR.w; e3 = e3 > 0.f ? e3 : ALPHA * e3;                   \
      const float w0 = ACUR[m].x > 0 ? exp2f(e0) : 0.f;                                \
      const float w1 = ACUR[m].y > 0 ? exp2f(e1) : 0.f;                                \
      const float w2 = ACUR[m].z > 0 ? exp2f(e2) : 0.f;                                \
      const float w3 = ACUR[m].w > 0 ? exp2f(e3) : 0.f;                                \
      bf16x4 pv = {(__bf16)w0, (__bf16)w1, (__bf16)w2, (__bf16)w3};                    \
      dsum[m] += (float)pv[0] + (float)pv[1] + (float)pv[2] + (float)pv[3];            \
      *(bf16x4*)&SBUF[il * 72 + j4 * 4] = pv;                                          \
    }                                                                                  \
    __syncthreads();                                                                   \
    /* P(32x64) @ Wh(64x256); B-operand straight from registers */                     \
    _Pragma("unroll")                                                                  \
    for (int kk = 0; kk < 2; ++kk) {                                                   \
      bf16x8 af[2];                                                                    \
      _Pragma("unroll")                                                                \
      for (int ri = 0; ri < 2; ++ri)                                                   \
        af[ri] = *(const bf16x8*)&SBUF[(ri * 16 + ln) * 72 + kk * 32 + quad * 8];      \
      _Pragma("unroll")                                                                \
      for (int ri = 0; ri < 2; ++ri)                                                   \
        _Pragma("unroll")                                                              \
        for (int oi = 0; oi < 4; ++oi)                                                 \
          acc[ri][oi] = __builtin_amdgcn_mfma_f32_16x16x32_bf16(                       \
              af[ri], bfr[kk][oi], acc[ri][oi], 0, 0, 0);                              \
    }                                                                                  \
    /* no second barrier: next body writes the other lds_s buffer; reuse of */         \
    /* this one is fenced by the NEXT body's barrier. */                               \
  }

__global__ __launch_bounds__(256, 4) void k3_attn(const int* __restrict__ adj,
                                                  const __bf16* __restrict__ whT,
                                                  const float* __restrict__ si_g,
                                                  const float* __restrict__ sj_g,
                                                  float* __restrict__ out) {
    __shared__ __bf16 lds_s0[32 * 72];   // double-buffered S tile (2 x 4.5 KB)
    __shared__ __bf16 lds_s1[32 * 72];
    __shared__ float  lds_denom[32];
    const int t = threadIdx.x;
    // XCD-chunked swizzle: 1024 % 8 == 0 -> bijective; each XCD owns 128
    // consecutive wgids = 4 whole batches, so its whT slice (2 MB) stays in L2.
    const int orig = blockIdx.x;
    const int wgid = (orig & 7) * 128 + (orig >> 3);
    const int b    = wgid >> 5;          // 32 blocks per batch
    const int i0   = (wgid & 31) << 5;   // 32-row i-tile
    const int w    = t >> 6;
    const int l    = t & 63;
    const int ln   = l & 15;
    const int quad = l >> 4;
    const int g    = t >> 4;   // 0..15
    const int j4   = t & 15;   // 0..15

    float si_r[2];
    #pragma unroll
    for (int m = 0; m < 2; ++m) si_r[m] = si_g[b * 1024 + i0 + m * 16 + g];

    float dsum[2] = {0.f, 0.f};
    f32x4 acc[2][4] = {};
    const __bf16* whTb = whT + (size_t)b * 256 * 1024;
    const int*    adjb = adj + ((size_t)(b * 1024 + i0)) * 1024;

    // double-buffered pipeline registers (static names)
    int4   a_c[2], a_n[2];
    float4 sj_c, sj_n;
    #pragma unroll
    for (int m = 0; m < 2; ++m)
        a_c[m] = *(const int4*)&adjb[(size_t)(m * 16 + g) * 1024 + j4 * 4];
    sj_c = *(const float4*)&sj_g[b * 1024 + j4 * 4];

    for (int jj = 0; jj < 8; ++jj) {
        K3_BODY(2 * jj,     a_c, sj_c, a_n, sj_n, lds_s0);
        K3_BODY(2 * jj + 1, a_n, sj_n, a_c, sj_c, lds_s1);
    }

    // reduce denominators across the 16 j4 lanes per row
    #pragma unroll
    for (int m = 0; m < 2; ++m) {
        float v = dsum[m];
        v += __shfl_xor(v, 1);
        v += __shfl_xor(v, 2);
        v += __shfl_xor(v, 4);
        v += __shfl_xor(v, 8);
        if (j4 == 0) lds_denom[m * 16 + g] = v;
    }
    __syncthreads();
    // epilogue: normalize, ELU, store
    #pragma unroll
    for (int ri = 0; ri < 2; ++ri) {
        #pragma unroll
        for (int q = 0; q < 4; ++q) {
            const int il = ri * 16 + quad * 4 + q;
            const float dinv = 1.0f / fmaxf(lds_denom[il], 1e-30f);
            #pragma unroll
            for (int oi = 0; oi < 4; ++oi) {
                const int o = w * 64 + oi * 16 + ln;
                const float v = acc[ri][oi][q] * dinv;
                const float r = v > 0.f ? v : __expf(v) - 1.f;
                out[((size_t)(b * 1024 + i0 + il)) * 256 + o] = r;
            }
        }
    }
}

extern "C" void kernel_launch(void* const* d_in, const int* in_sizes, int n_in,
                              void* d_out, int out_size, void* d_ws, size_t ws_size,
                              hipStream_t stream) {
    const float* h   = (const float*)d_in[0];
    const int*   adj = (const int*)d_in[1];
    const float* W   = (const float*)d_in[2];
    const float* a   = (const float*)d_in[3];
    float* out = (float*)d_out;

    __bf16* whT = (__bf16*)d_ws;                              // 16 MiB
    float*  si  = (float*)((char*)d_ws + (size_t)16777216);   // 128 KiB
    float*  sj  = (float*)((char*)d_ws + (size_t)16777216 + 131072);

    k1_gemm1<<<512, 256, 0, stream>>>(h, W, a, whT, si, sj);
    k3_attn<<<1024, 256, 0, stream>>>(adj, whT, si, sj, out);
}

// Round 3
// 256.653 us; speedup vs baseline: 1.1770x; 1.1770x over previous
//
#include <hip/hip_runtime.h>
#include <hip/hip_bf16.h>

// GAT layer: B=32, N=1024, IN_F=OUT_F=256, alpha=0.2
//  k1: WhT[b][o][n] = bf16(h @ W^T), MFMA; epilogue via LDS -> coalesced 128B
//      row-segment writes; fused si/sj (= Wh @ a1/a2), pre-scaled by log2(e)
//  k3: fused adj-read + masked-softmax attention + PV MFMA + ELU.
//      64-row i-tiles (round-1 geometry: round-2 proved occupancy was not the
//      limiter). KEY FIX: raw s_barrier + lgkmcnt(0) instead of __syncthreads
//      -> no vmcnt(0) drain at the 16 per-body barriers, so the distance-2
//      adj/sj register prefetch and the bfr whT loads stay in flight across
//      barriers with compiler-counted vmcnt waits (T4). setprio(1) around MFMA.

#define ALPHA 0.2f
#define LOG2E 1.44269504f

typedef __bf16 bf16x8 __attribute__((ext_vector_type(8)));
typedef __bf16 bf16x4 __attribute__((ext_vector_type(4)));
typedef float  f32x4  __attribute__((ext_vector_type(4)));
typedef unsigned long long u64;

// ---------------- k1: Wh = h @ W^T -> whT (bf16) + si/sj ----------------
// grid 512 x 256 thr; block = 64 n-rows x 256 o, K chunks of 64, reg-prefetched.
__global__ __launch_bounds__(256) void k1_gemm1(const float* __restrict__ h,
                                                const float* __restrict__ W,
                                                const float* __restrict__ a_g,
                                                __bf16* __restrict__ whT,
                                                float* __restrict__ si,
                                                float* __restrict__ sj) {
    __shared__ __bf16 hA[64 * 72];
    __shared__ __bf16 hB[256 * 72];   // W tiles; reused as [o][n] out-staging
    __shared__ float  red[512];
    const int t    = threadIdx.x;
    const int r0   = blockIdx.x * 64;
    const int b    = r0 >> 10;
    const int n0   = r0 & 1023;
    const int w    = t >> 6;
    const int l    = t & 63;
    const int ln   = l & 15;
    const int quad = l >> 4;

    f32x4 acc[4][4] = {};
    float4 ha_r[4], wb_r[16];

    // preload chunk 0
    #pragma unroll
    for (int it = 0; it < 4; ++it)
        ha_r[it] = *(const float4*)&h[(size_t)(r0 + it * 16 + (t >> 4)) * 256 + (t & 15) * 4];
    #pragma unroll
    for (int it = 0; it < 16; ++it)
        wb_r[it] = *(const float4*)&W[(size_t)(it * 16 + (t >> 4)) * 256 + (t & 15) * 4];

    for (int kc = 0; kc < 4; ++kc) {
        // write staged chunk to LDS (fp32 -> bf16)
        #pragma unroll
        for (int it = 0; it < 4; ++it) {
            const float4 v = ha_r[it];
            bf16x4 pv = {(__bf16)v.x, (__bf16)v.y, (__bf16)v.z, (__bf16)v.w};
            *(bf16x4*)&hA[(it * 16 + (t >> 4)) * 72 + (t & 15) * 4] = pv;
        }
        #pragma unroll
        for (int it = 0; it < 16; ++it) {
            const float4 v = wb_r[it];
            bf16x4 pv = {(__bf16)v.x, (__bf16)v.y, (__bf16)v.z, (__bf16)v.w};
            *(bf16x4*)&hB[(it * 16 + (t >> 4)) * 72 + (t & 15) * 4] = pv;
        }
        __syncthreads();
        // prefetch next chunk while MFMA runs
        if (kc < 3) {
            const int k0 = (kc + 1) * 64;
            #pragma unroll
            for (int it = 0; it < 4; ++it)
                ha_r[it] = *(const float4*)&h[(size_t)(r0 + it * 16 + (t >> 4)) * 256 + k0 + (t & 15) * 4];
            #pragma unroll
            for (int it = 0; it < 16; ++it)
                wb_r[it] = *(const float4*)&W[(size_t)(it * 16 + (t >> 4)) * 256 + k0 + (t & 15) * 4];
        }
        #pragma unroll
        for (int kk = 0; kk < 2; ++kk) {
            bf16x8 af[4], bfr[4];
            #pragma unroll
            for (int ri = 0; ri < 4; ++ri)
                af[ri] = *(const bf16x8*)&hA[(ri * 16 + ln) * 72 + kk * 32 + quad * 8];
            #pragma unroll
            for (int oi = 0; oi < 4; ++oi)
                bfr[oi] = *(const bf16x8*)&hB[(w * 64 + oi * 16 + ln) * 72 + kk * 32 + quad * 8];
            #pragma unroll
            for (int ri = 0; ri < 4; ++ri)
                #pragma unroll
                for (int oi = 0; oi < 4; ++oi)
                    acc[ri][oi] = __builtin_amdgcn_mfma_f32_16x16x32_bf16(
                        af[ri], bfr[oi], acc[ri][oi], 0, 0, 0);
        }
        __syncthreads();
    }

    // stage acc -> hB as [o][n_local] (stride 72, conflict-light)
    #pragma unroll
    for (int ri = 0; ri < 4; ++ri) {
        const int n = ri * 16 + quad * 4;
        #pragma unroll
        for (int oi = 0; oi < 4; ++oi) {
            const int o = w * 64 + oi * 16 + ln;
            bf16x4 pv = {(__bf16)acc[ri][oi][0], (__bf16)acc[ri][oi][1],
                         (__bf16)acc[ri][oi][2], (__bf16)acc[ri][oi][3]};
            *(bf16x4*)&hB[o * 72 + n] = pv;
        }
    }
    __syncthreads();

    // whT writes: wave w covers o in [w*64, w*64+64); 8 rows x 128B per instr
    #pragma unroll
    for (int it = 0; it < 8; ++it) {
        const int o   = w * 64 + it * 8 + (l >> 3);
        const int seg = l & 7;
        const bf16x8 v = *(const bf16x8*)&hB[o * 72 + seg * 8];
        *(bf16x8*)&whT[((size_t)b * 256 + o) * 1024 + n0 + seg * 8] = v;
    }

    // fused si/sj: wave w sums o-range [w*64, w*64+64) for n = lane
    {
        float s1 = 0.f, s2 = 0.f;
        #pragma unroll 8
        for (int oi = 0; oi < 64; ++oi) {
            const int o = w * 64 + oi;
            const float v = (float)hB[o * 72 + l];
            s1 += v * a_g[o];
            s2 += v * a_g[256 + o];
        }
        red[w * 64 + l]       = s1;
        red[256 + w * 64 + l] = s2;
    }
    __syncthreads();
    // pre-scale by log2(e): leaky-relu commutes with a positive scale, so
    // k3 can use native v_exp_f32 (exp2f) directly.
    if (t < 64) {
        si[b * 1024 + n0 + t] =
            (red[t] + red[64 + t] + red[128 + t] + red[192 + t]) * LOG2E;
    } else if (t < 128) {
        const int n = t - 64;
        sj[b * 1024 + n0 + n] =
            (red[256 + n] + red[320 + n] + red[384 + n] + red[448 + n]) * LOG2E;
    }
}

// ---------------- k3: fused attention (64-row tiles, counted-vmcnt pipeline) ----------------
// grid 512 (XCD-chunked), 256 thr (4 waves). One RAW barrier per j-chunk:
// lgkmcnt(0) only -- global loads stay in flight across barriers, the compiler
// emits counted vmcnt before each consumer (pre-MFMA wait = vmcnt(5), keeping
// the distance-2 adj prefetch outstanding). A/SJ are reloaded in place for
// chunk JC+2 after consumption (period-2 rotation, static names).
#define K3_BODY(JC, A, SJ, SBUF)                                                       \
  {                                                                                    \
    const int j0 = (JC) * 64;                                                          \
    /* B-fragments for this chunk: issued first so the pre-MFMA counted wait */        \
    /* (vmcnt(5)) excludes the newer adj/sj prefetch loads */                          \
    bf16x8 bfr[2][4];                                                                  \
    _Pragma("unroll")                                                                  \
    for (int kk = 0; kk < 2; ++kk)                                                     \
      _Pragma("unroll")                                                                \
      for (int oi = 0; oi < 4; ++oi)                                                   \
        bfr[kk][oi] = *(const bf16x8*)&whTb[                                           \
            (size_t)(w * 64 + oi * 16 + ln) * 1024 + j0 + kk * 32 + quad * 8];         \
    /* S tile: w = adj ? exp2(leakyrelu(si+sj)) : 0   (si/sj pre-scaled) */            \
    _Pragma("unroll")                                                                  \
    for (int m = 0; m < 4; ++m) {                                                      \
      const int il = m * 16 + g;                                                       \
      float e0 = si_r[m] + SJ.x; e0 = e0 > 0.f ? e0 : ALPHA * e0;                      \
      float e1 = si_r[m] + SJ.y; e1 = e1 > 0.f ? e1 : ALPHA * e1;                      \
      float e2 = si_r[m] + SJ.z; e2 = e2 > 0.f ? e2 : ALPHA * e2;                      \
      float e3 = si_r[m] + SJ.w; e3 = e3 > 0.f ? e3 : ALPHA * e3;                      \
      const float w0 = A[m].x > 0 ? exp2f(e0) : 0.f;                                   \
      const float w1 = A[m].y > 0 ? exp2f(e1) : 0.f;                                   \
      const float w2 = A[m].z > 0 ? exp2f(e2) : 0.f;                                   \
      const float w3 = A[m].w > 0 ? exp2f(e3) : 0.f;                                   \
      bf16x4 pv = {(__bf16)w0, (__bf16)w1, (__bf16)w2, (__bf16)w3};                    \
      dsum[m] += (float)pv[0] + (float)pv[1] + (float)pv[2] + (float)pv[3];            \
      *(bf16x4*)&SBUF[il * 72 + j4 * 4] = pv;                                          \
    }                                                                                  \
    /* reload A/SJ in place with chunk JC+2 (regs consumed above); these stay */       \
    /* in flight across TWO raw barriers before being waited */                        \
    if ((JC) + 2 < 16) {                                                               \
      _Pragma("unroll")                                                                \
      for (int m = 0; m < 4; ++m)                                                      \
        A[m] = *(const int4*)&adjb[(size_t)(m * 16 + g) * 1024 + j0 + 128 + j4 * 4];   \
      SJ = *(const float4*)&sj_g[b * 1024 + j0 + 128 + j4 * 4];                        \
    }                                                                                  \
    /* raw barrier: drain LDS writes only, NOT vmcnt (T4) */                           \
    asm volatile("s_waitcnt lgkmcnt(0)");                                              \
    __builtin_amdgcn_s_barrier();                                                      \
    /* P(64x64) @ Wh(64x256); compiler emits counted vmcnt for bfr here */             \
    __builtin_amdgcn_s_setprio(1);                                                     \
    _Pragma("unroll")                                                                  \
    for (int kk = 0; kk < 2; ++kk) {                                                   \
      bf16x8 af[4];                                                                    \
      _Pragma("unroll")                                                                \
      for (int ri = 0; ri < 4; ++ri)                                                   \
        af[ri] = *(const bf16x8*)&SBUF[(ri * 16 + ln) * 72 + kk * 32 + quad * 8];      \
      _Pragma("unroll")                                                                \
      for (int ri = 0; ri < 4; ++ri)                                                   \
        _Pragma("unroll")                                                              \
        for (int oi = 0; oi < 4; ++oi)                                                 \
          acc[ri][oi] = __builtin_amdgcn_mfma_f32_16x16x32_bf16(                       \
              af[ri], bfr[kk][oi], acc[ri][oi], 0, 0, 0);                              \
    }                                                                                  \
    __builtin_amdgcn_s_setprio(0);                                                     \
    /* no second barrier: buffer reuse (jc+2 writes) is fenced by the NEXT */          \
    /* body's barrier, and reads are register-consumed before arrival */               \
  }

__global__ __launch_bounds__(256, 2) void k3_attn(const int* __restrict__ adj,
                                                  const __bf16* __restrict__ whT,
                                                  const float* __restrict__ si_g,
                                                  const float* __restrict__ sj_g,
                                                  float* __restrict__ out) {
    __shared__ __bf16 lds_s0[64 * 72];   // double-buffered S tile (2 x 9 KB)
    __shared__ __bf16 lds_s1[64 * 72];
    __shared__ float  lds_denom[64];
    const int t = threadIdx.x;
    // XCD-chunked swizzle: 512 % 8 == 0 -> bijective; each XCD owns 64
    // consecutive wgids = 4 whole batches, so its whT slice (2 MB) stays in L2.
    const int orig = blockIdx.x;
    const int wgid = (orig & 7) * 64 + (orig >> 3);
    const int b    = wgid >> 4;
    const int i0   = (wgid & 15) << 6;
    const int w    = t >> 6;
    const int l    = t & 63;
    const int ln   = l & 15;
    const int quad = l >> 4;
    const int g    = t >> 4;   // 0..15
    const int j4   = t & 15;   // 0..15

    float si_r[4];
    #pragma unroll
    for (int m = 0; m < 4; ++m) si_r[m] = si_g[b * 1024 + i0 + m * 16 + g];

    float dsum[4] = {0.f, 0.f, 0.f, 0.f};
    f32x4 acc[4][4] = {};
    const __bf16* whTb = whT + (size_t)b * 256 * 1024;
    const int*    adjb = adj + ((size_t)(b * 1024 + i0)) * 1024;

    // distance-2 prefetch pipeline registers (static names, period-2 rotation)
    int4   a_c[4], a_n[4];
    float4 sj_c, sj_n;
    #pragma unroll
    for (int m = 0; m < 4; ++m)
        a_c[m] = *(const int4*)&adjb[(size_t)(m * 16 + g) * 1024 + j4 * 4];
    sj_c = *(const float4*)&sj_g[b * 1024 + j4 * 4];
    #pragma unroll
    for (int m = 0; m < 4; ++m)
        a_n[m] = *(const int4*)&adjb[(size_t)(m * 16 + g) * 1024 + 64 + j4 * 4];
    sj_n = *(const float4*)&sj_g[b * 1024 + 64 + j4 * 4];

    for (int jj = 0; jj < 8; ++jj) {
        K3_BODY(2 * jj,     a_c, sj_c, lds_s0);
        K3_BODY(2 * jj + 1, a_n, sj_n, lds_s1);
    }

    // reduce denominators across the 16 j4 lanes per row
    #pragma unroll
    for (int m = 0; m < 4; ++m) {
        float v = dsum[m];
        v += __shfl_xor(v, 1);
        v += __shfl_xor(v, 2);
        v += __shfl_xor(v, 4);
        v += __shfl_xor(v, 8);
        if (j4 == 0) lds_denom[m * 16 + g] = v;
    }
    __syncthreads();
    // epilogue: normalize, ELU, store
    #pragma unroll
    for (int ri = 0; ri < 4; ++ri) {
        #pragma unroll
        for (int q = 0; q < 4; ++q) {
            const int il = ri * 16 + quad * 4 + q;
            const float dinv = 1.0f / fmaxf(lds_denom[il], 1e-30f);
            #pragma unroll
            for (int oi = 0; oi < 4; ++oi) {
                const int o = w * 64 + oi * 16 + ln;
                const float v = acc[ri][oi][q] * dinv;
                const float r = v > 0.f ? v : __expf(v) - 1.f;
                out[((size_t)(b * 1024 + i0 + il)) * 256 + o] = r;
            }
        }
    }
}

extern "C" void kernel_launch(void* const* d_in, const int* in_sizes, int n_in,
                              void* d_out, int out_size, void* d_ws, size_t ws_size,
                              hipStream_t stream) {
    const float* h   = (const float*)d_in[0];
    const int*   adj = (const int*)d_in[1];
    const float* W   = (const float*)d_in[2];
    const float* a   = (const float*)d_in[3];
    float* out = (float*)d_out;

    __bf16* whT = (__bf16*)d_ws;                              // 16 MiB
    float*  si  = (float*)((char*)d_ws + (size_t)16777216);   // 128 KiB
    float*  sj  = (float*)((char*)d_ws + (size_t)16777216 + 131072);

    k1_gemm1<<<512, 256, 0, stream>>>(h, W, a, whT, si, sj);
    k3_attn<<<512, 256, 0, stream>>>(adj, whT, si, sj, out);
}